// Round 7
// baseline (2346.690 us; speedup 1.0000x reference)
//
#include <hip/hip_runtime.h>

#define BB 32
#define CC 128
#define HH 12
#define WW 1200
#define DIN 1536
#define FIXD 768
#define OVL 4
#define GG 6
#define DD 512
#define KK 1024
#define TT 300
#define NV 9600        /* B*T vectors per group */
#define MROWS 38400    /* B*W */

// workspace layout (float offsets)
#define Y_OFF     0          /* 29,491,200 floats; Tab overlays this after k_znorm */
#define ET_OFF    29491200
#define NORM_OFF  32636928
#define BEST_OFF  32643072   /* 57600 uint64 = 115200 floats */
#define LOSS_OFF  32758272
#define ZN_OFF    32758336   /* 57600 floats */

// LDS column swizzle for B-side tiles (kept from R6; placement-only)
#define BSWZ(c) ((c) + 4 * ((c) >> 5))

// ---------------- K1: proj_down fp32 GEMM, 128x128, BK=32, reg-prefetch ------
// Y[n][f] = sum_k z[b*1843200 + k*1200 + w] * w_down[f*1536+k];  n = b*1200+w
// Per-output accumulation is strictly k-sequential -> bit-identical Y to
// R3/R5/R6 (argmin-critical: do NOT change the fmaf chain order).
__global__ __launch_bounds__(256) void k_gemm_down(const float* __restrict__ z,
                                                   const float* __restrict__ w_down,
                                                   float* __restrict__ Y) {
    __shared__ float As[32][132];
    __shared__ float Bs[32][140];
    const int n0 = blockIdx.x * 128, f0 = blockIdx.y * 128;
    const int tid = threadIdx.x;
    // A staging: row fixed per thread (128 rows), 16 k-slots (k = ak0 + 2*i)
    const int arow = tid & 127;
    const int ak0 = tid >> 7;           // 0..1
    const int nA = n0 + arow;
    const int bA = nA / WW, wA = nA - bA * WW;
    const size_t zbase = (size_t)bA * (CC * HH * WW) + wA;
    // B staging: col = tid>>1 (128 cols), four float4 (q = bq + 2*i)
    const int bcol = tid >> 1, bq = tid & 1;
    const int bsc = BSWZ(bcol);
    // compute thread grid 16x16
    const int trow = tid >> 4, tcol = tid & 15;
    const int bread = tcol * 8 + 4 * (tcol >> 2);
    float acc[8][8] = {};
    float pa[16];
    float4 pb[4];
    // prologue: load tile kt=0 into regs
    #pragma unroll
    for (int i = 0; i < 16; i++) pa[i] = z[zbase + (size_t)(ak0 + 2 * i) * WW];
    #pragma unroll
    for (int i = 0; i < 4; i++)
        pb[i] = *(const float4*)&w_down[(size_t)(f0 + bcol) * DIN + (bq + 2 * i) * 4];
    for (int kt = 0; kt < DIN; kt += 32) {
        // store prefetched tile to LDS
        #pragma unroll
        for (int i = 0; i < 16; i++) As[ak0 + 2 * i][arow] = pa[i];
        #pragma unroll
        for (int i = 0; i < 4; i++) {
            const int q = bq + 2 * i;       // 0..7
            Bs[q * 4 + 0][bsc] = pb[i].x;
            Bs[q * 4 + 1][bsc] = pb[i].y;
            Bs[q * 4 + 2][bsc] = pb[i].z;
            Bs[q * 4 + 3][bsc] = pb[i].w;
        }
        __syncthreads();
        if (kt + 32 < DIN) {
            #pragma unroll
            for (int i = 0; i < 16; i++)
                pa[i] = z[zbase + (size_t)(kt + 32 + ak0 + 2 * i) * WW];
            #pragma unroll
            for (int i = 0; i < 4; i++)
                pb[i] = *(const float4*)&w_down[(size_t)(f0 + bcol) * DIN + kt + 32 + (bq + 2 * i) * 4];
        }
        #pragma unroll
        for (int k = 0; k < 32; k++) {
            float av[8], bv[8];
            *(float4*)&av[0] = *(const float4*)&As[k][trow * 8];
            *(float4*)&av[4] = *(const float4*)&As[k][trow * 8 + 4];
            *(float4*)&bv[0] = *(const float4*)&Bs[k][bread];
            *(float4*)&bv[4] = *(const float4*)&Bs[k][bread + 4];
            #pragma unroll
            for (int i = 0; i < 8; i++)
                #pragma unroll
                for (int j = 0; j < 8; j++)
                    acc[i][j] = fmaf(av[i], bv[j], acc[i][j]);
        }
        __syncthreads();
    }
    #pragma unroll
    for (int i = 0; i < 8; i++) {
        float4 o0, o1;
        o0.x = acc[i][0]; o0.y = acc[i][1]; o0.z = acc[i][2]; o0.w = acc[i][3];
        o1.x = acc[i][4]; o1.y = acc[i][5]; o1.z = acc[i][6]; o1.w = acc[i][7];
        float* yr = &Y[(size_t)(n0 + trow * 8 + i) * FIXD + f0 + tcol * 8];
        *(float4*)yr = o0;
        *(float4*)(yr + 4) = o1;
    }
}

// ---------------- K2: transpose codebook emb(g,d,k) -> ET(g,k,d) ----------------
__global__ __launch_bounds__(256) void k_transpose(const float* __restrict__ emb,
                                                   float* __restrict__ ET) {
    int i = blockIdx.x * 256 + threadIdx.x;
    if (i >= GG * KK * DD) return;
    int d = i & 511;
    int rem = i >> 9;
    int k = rem & 1023;
    int g = rem >> 10;
    ET[i] = emb[((g * DD + d) << 10) + k];
}

// ---------------- K2b: per-code squared norms (fp64 accumulate) ----------------
__global__ __launch_bounds__(64) void k_norms(const float* __restrict__ ET,
                                              float* __restrict__ norms) {
    const int code = blockIdx.x;
    const int lane = threadIdx.x;
    const float* row = ET + code * DD;
    double s = 0.0;
    #pragma unroll
    for (int r = 0; r < 8; r++) {
        float v = row[lane + r * 64];
        s += (double)v * (double)v;
    }
    #pragma unroll
    for (int off = 32; off; off >>= 1) s += __shfl_down(s, off);
    if (lane == 0) norms[code] = (float)s;
}

// ---------------- K3: distance GEMM + fused argmin, BK=32, reg-prefetch ------
// Scores are exact-fp32, d-sequential -> bit-identical to R5/R6 (argmin-critical).
__global__ __launch_bounds__(256) void k_dist2(const float* __restrict__ Y,
                                               const float* __restrict__ ET,
                                               const float* __restrict__ norms,
                                               unsigned long long* __restrict__ best) {
    __shared__ float Zs[32][68];
    __shared__ float Es[32][140];
    __shared__ unsigned long long red[64][17];
    const int vt = blockIdx.x;
    const int ct = blockIdx.y;
    const int g  = blockIdx.z;
    const int tid = threadIdx.x;
    const int rgrp = tid >> 4, cgrp = tid & 15;
    const int rbase = rgrp * 4;
    const int eread = cgrp * 8 + 4 * (cgrp >> 2);
    const int v0 = vt * 64, c0 = ct * 128;
    const float* ETg = ET + (size_t)g * KK * DD;

    // Z staging: zrow = tid>>2 (64 rows), two float4 at d = zq*4 and 16+zq*4
    const int zrow = tid >> 2, zq = tid & 3;
    const int vz = v0 + zrow;
    const int bz = vz / TT, tz = vz - bz * TT;
    // E staging: two codes per thread (flat = tid, tid+256), two float4 each
    const int ecode0 = tid >> 2;            // 0..63
    const int ecode1 = 64 + (tid >> 2);     // 64..127
    const int eq = tid & 3;
    const int esc0 = BSWZ(ecode0), esc1 = BSWZ(ecode1);

    float acc[4][8] = {};
    float4 pz[2], pe[4];

    // prologue: load kt=0 tile
    {
        const int p0 = g * DD;
        const int s = p0 / FIXD, f0 = p0 - s * FIXD;
        const float* yb = &Y[(size_t)(bz * WW + tz * OVL + s) * FIXD + f0];
        pz[0] = *(const float4*)&yb[zq * 4];
        pz[1] = *(const float4*)&yb[16 + zq * 4];
        pe[0] = *(const float4*)&ETg[(size_t)(c0 + ecode0) * DD + eq * 4];
        pe[1] = *(const float4*)&ETg[(size_t)(c0 + ecode0) * DD + 16 + eq * 4];
        pe[2] = *(const float4*)&ETg[(size_t)(c0 + ecode1) * DD + eq * 4];
        pe[3] = *(const float4*)&ETg[(size_t)(c0 + ecode1) * DD + 16 + eq * 4];
    }
    for (int kt = 0; kt < DD; kt += 32) {
        // store prefetched tile
        {
            Zs[zq * 4 + 0][zrow] = pz[0].x;
            Zs[zq * 4 + 1][zrow] = pz[0].y;
            Zs[zq * 4 + 2][zrow] = pz[0].z;
            Zs[zq * 4 + 3][zrow] = pz[0].w;
            Zs[16 + zq * 4 + 0][zrow] = pz[1].x;
            Zs[16 + zq * 4 + 1][zrow] = pz[1].y;
            Zs[16 + zq * 4 + 2][zrow] = pz[1].z;
            Zs[16 + zq * 4 + 3][zrow] = pz[1].w;
            Es[eq * 4 + 0][esc0] = pe[0].x;
            Es[eq * 4 + 1][esc0] = pe[0].y;
            Es[eq * 4 + 2][esc0] = pe[0].z;
            Es[eq * 4 + 3][esc0] = pe[0].w;
            Es[16 + eq * 4 + 0][esc0] = pe[1].x;
            Es[16 + eq * 4 + 1][esc0] = pe[1].y;
            Es[16 + eq * 4 + 2][esc0] = pe[1].z;
            Es[16 + eq * 4 + 3][esc0] = pe[1].w;
            Es[eq * 4 + 0][esc1] = pe[2].x;
            Es[eq * 4 + 1][esc1] = pe[2].y;
            Es[eq * 4 + 2][esc1] = pe[2].z;
            Es[eq * 4 + 3][esc1] = pe[2].w;
            Es[16 + eq * 4 + 0][esc1] = pe[3].x;
            Es[16 + eq * 4 + 1][esc1] = pe[3].y;
            Es[16 + eq * 4 + 2][esc1] = pe[3].z;
            Es[16 + eq * 4 + 3][esc1] = pe[3].w;
        }
        __syncthreads();
        if (kt + 32 < DD) {
            const int p0 = g * DD + kt + 32;
            const int s = p0 / FIXD, f0 = p0 - s * FIXD;
            const float* yb = &Y[(size_t)(bz * WW + tz * OVL + s) * FIXD + f0];
            pz[0] = *(const float4*)&yb[zq * 4];
            pz[1] = *(const float4*)&yb[16 + zq * 4];
            pe[0] = *(const float4*)&ETg[(size_t)(c0 + ecode0) * DD + kt + 32 + eq * 4];
            pe[1] = *(const float4*)&ETg[(size_t)(c0 + ecode0) * DD + kt + 48 + eq * 4];
            pe[2] = *(const float4*)&ETg[(size_t)(c0 + ecode1) * DD + kt + 32 + eq * 4];
            pe[3] = *(const float4*)&ETg[(size_t)(c0 + ecode1) * DD + kt + 48 + eq * 4];
        }
        #pragma unroll
        for (int k = 0; k < 32; k++) {
            const float4 z4 = *(const float4*)&Zs[k][rbase];
            const float4 ea = *(const float4*)&Es[k][eread];
            const float4 eb = *(const float4*)&Es[k][eread + 4];
            const float zv[4] = {z4.x, z4.y, z4.z, z4.w};
            const float ev[8] = {ea.x, ea.y, ea.z, ea.w, eb.x, eb.y, eb.z, eb.w};
            #pragma unroll
            for (int i = 0; i < 4; i++)
                #pragma unroll
                for (int j = 0; j < 8; j++)
                    acc[i][j] = fmaf(zv[i], ev[j], acc[i][j]);
        }
        __syncthreads();
    }

    unsigned long long kbest[4];
    #pragma unroll
    for (int i = 0; i < 4; i++) kbest[i] = ~0ull;
    #pragma unroll
    for (int j = 0; j < 8; j++) {
        const int c = c0 + cgrp * 8 + j;
        const float nrm = norms[(g << 10) + c];
        #pragma unroll
        for (int i = 0; i < 4; i++) {
            float score = nrm - 2.0f * acc[i][j];
            unsigned u = __float_as_uint(score);
            u = (u & 0x80000000u) ? ~u : (u | 0x80000000u);
            unsigned long long key = ((unsigned long long)u << 32) | (unsigned)c;
            if (key < kbest[i]) kbest[i] = key;
        }
    }
    #pragma unroll
    for (int i = 0; i < 4; i++) red[rbase + i][cgrp] = kbest[i];
    __syncthreads();
    if (tid < 64) {
        unsigned long long b = red[tid][0];
        #pragma unroll
        for (int j = 1; j < 16; j++) {
            unsigned long long v = red[tid][j];
            if (v < b) b = v;
        }
        atomicMin(&best[g * NV + v0 + tid], b);
    }
}

// ---------------- K4a: per-vector |z|^2 (for loss via score identity) --------
__global__ __launch_bounds__(256) void k_znorm(const float* __restrict__ Y,
                                               float* __restrict__ znorm) {
    const int v = blockIdx.x * 4 + (threadIdx.x >> 6);   // 0..57599
    const int lane = threadIdx.x & 63;
    const int g = v / NV;
    const int r = v - g * NV;
    const int b = r / TT, t = r - b * TT;
    float s = 0.0f;
    #pragma unroll
    for (int rr = 0; rr < 8; rr++) {
        const int d = lane + rr * 64;
        const int p = g * DD + d;
        const int sg = p / FIXD, f = p - sg * FIXD;
        const float x = Y[(size_t)(b * WW + t * OVL + sg) * FIXD + f];
        s = fmaf(x, x, s);
    }
    #pragma unroll
    for (int off = 32; off; off >>= 1) s += __shfl_down(s, off);
    if (lane == 0) znorm[v] = s;
}

// ---------------- K4b: loss = sum_v (best_score_v + |z_v|^2) -----------------
// best key high word is a bijective monotone map of the fp32 score: decode it.
__global__ __launch_bounds__(256) void k_sumloss(const unsigned long long* __restrict__ best,
                                                 const float* __restrict__ znorm,
                                                 float* __restrict__ lossAcc) {
    const int v = blockIdx.x * 256 + threadIdx.x;        // 225 blocks * 256 = 57600
    const unsigned long long key = best[v];
    const unsigned u = (unsigned)(key >> 32);
    const unsigned x = (u & 0x80000000u) ? (u & 0x7fffffffu) : ~u;
    float s = __uint_as_float(x) + znorm[v];
    __shared__ float red[256];
    red[threadIdx.x] = s;
    __syncthreads();
    for (int off = 128; off; off >>= 1) {
        if (threadIdx.x < off) red[threadIdx.x] += red[threadIdx.x + off];
        __syncthreads();
    }
    if (threadIdx.x == 0) atomicAdd(lossAcc, red[0]);
}

// ---------------- K5a: per-(segment,code) up-projection table ----------------
__constant__ int SEG_G[8]  = {0, 1, 1, 2, 3, 4, 4, 5};
__constant__ int SEG_D0[8] = {0, 0, 256, 0, 0, 0, 256, 0};
__constant__ int SEG_L[8]  = {512, 256, 256, 512, 512, 256, 256, 512};
__constant__ int SEG_F0[8] = {0, 512, 0, 256, 0, 512, 0, 256};

__global__ __launch_bounds__(256) void k_table(const float* __restrict__ ET,
                                               const float* __restrict__ w_up,
                                               float* __restrict__ Tab) {
    __shared__ float As[16][68];
    __shared__ float Bs[16][140];
    const int bm = blockIdx.x;
    const int bn = blockIdx.y;
    const int seg = blockIdx.z;
    const int g = SEG_G[seg], d0 = SEG_D0[seg], len = SEG_L[seg], fb = SEG_F0[seg];
    const int tid = threadIdx.x;
    const int k0 = bm * 64, dout0 = bn * 128;
    const int arow = tid >> 2, aq = tid & 3;
    const int rbase = (tid >> 4) << 2;
    const int cgrp = tid & 15;
    const int bread = cgrp * 8 + 4 * (cgrp >> 2);
    const float* ETg = ET + (size_t)(g << 10) * DD;
    float acc[4][8] = {};
    for (int kt = 0; kt < len; kt += 16) {
        {
            const float4 v = *(const float4*)&ETg[(size_t)(k0 + arow) * DD + d0 + kt + aq * 4];
            As[aq * 4 + 0][arow] = v.x;
            As[aq * 4 + 1][arow] = v.y;
            As[aq * 4 + 2][arow] = v.z;
            As[aq * 4 + 3][arow] = v.w;
        }
        #pragma unroll
        for (int i = 0; i < 2; i++) {
            int fl = tid + i * 256;
            int col = fl >> 2, q = fl & 3;
            const int sc = BSWZ(col);
            const float4 v = *(const float4*)&w_up[(size_t)(dout0 + col) * FIXD + fb + kt + q * 4];
            Bs[q * 4 + 0][sc] = v.x;
            Bs[q * 4 + 1][sc] = v.y;
            Bs[q * 4 + 2][sc] = v.z;
            Bs[q * 4 + 3][sc] = v.w;
        }
        __syncthreads();
        #pragma unroll
        for (int k = 0; k < 16; k++) {
            const float4 a  = *(const float4*)&As[k][rbase];
            const float4 ba = *(const float4*)&Bs[k][bread];
            const float4 bb = *(const float4*)&Bs[k][bread + 4];
            const float av[4] = {a.x, a.y, a.z, a.w};
            const float bv[8] = {ba.x, ba.y, ba.z, ba.w, bb.x, bb.y, bb.z, bb.w};
            #pragma unroll
            for (int i = 0; i < 4; i++)
                #pragma unroll
                for (int j = 0; j < 8; j++)
                    acc[i][j] = fmaf(av[i], bv[j], acc[i][j]);
        }
        __syncthreads();
    }
    #pragma unroll
    for (int i = 0; i < 4; i++) {
        float4 o0, o1;
        o0.x = acc[i][0]; o0.y = acc[i][1]; o0.z = acc[i][2]; o0.w = acc[i][3];
        o1.x = acc[i][4]; o1.y = acc[i][5]; o1.z = acc[i][6]; o1.w = acc[i][7];
        float* tr = &Tab[(size_t)((seg << 10) + k0 + rbase + i) * DIN + dout0 + cgrp * 8];
        *(float4*)tr = o0;
        *(float4*)(tr + 4) = o1;
    }
}

// ---------------- K5b: gather-add scatter to output ----------------
__global__ __launch_bounds__(256) void k_scatter(const float* __restrict__ Tab,
                                                 const unsigned long long* __restrict__ best,
                                                 float* __restrict__ out) {
    __shared__ float Ls[64][65];
    const int dt = blockIdx.x;
    const int wt = blockIdx.y;
    const int b  = blockIdx.z;
    const int dout0 = dt * 64, w0 = wt * 64;
    const int wlim = (WW - w0 < 64) ? (WW - w0) : 64;
    const int tid = threadIdx.x;
    const int wi = tid >> 2, q = tid & 3;

    if (wi < wlim) {
        const int w = w0 + wi;
        const int s = w & 3;
        const int t = w >> 2;
        const int gEt[4] = {0, 1, 3, 4};
        const int gOt[4] = {1, 2, 4, 5};
        int ce = (int)(unsigned)best[gEt[s] * NV + b * TT + t];
        int co = (int)(unsigned)best[gOt[s] * NV + b * TT + t];
        size_t rowE = (size_t)(((2 * s) << 10) + ce) * DIN;
        size_t rowO = (size_t)(((2 * s + 1) << 10) + co) * DIN;
        #pragma unroll
        for (int rep = 0; rep < 4; rep++) {
            const int doff = rep * 16 + q * 4;
            const float4 a = *(const float4*)&Tab[rowE + dout0 + doff];
            const float4 c = *(const float4*)&Tab[rowO + dout0 + doff];
            Ls[wi][doff + 0] = a.x + c.x;
            Ls[wi][doff + 1] = a.y + c.y;
            Ls[wi][doff + 2] = a.z + c.z;
            Ls[wi][doff + 3] = a.w + c.w;
        }
    }
    __syncthreads();
    const size_t obase = (size_t)b * (CC * HH * WW) + (size_t)dout0 * WW + w0;
    #pragma unroll
    for (int i = 0; i < 16; i++) {
        int flat = tid + i * 256;
        int dr = flat >> 6, wj = flat & 63;
        if (wj < wlim) out[obase + (size_t)dr * WW + wj] = Ls[wj][dr];
    }
}

// ---------------- K6: finalize loss scalar ----------------
__global__ void k_finish(const float* __restrict__ lossAcc, float* __restrict__ out) {
    if (threadIdx.x == 0)
        out[58982400] = lossAcc[0] * (0.25f / 29491200.0f);
}

extern "C" void kernel_launch(void* const* d_in, const int* in_sizes, int n_in,
                              void* d_out, int out_size, void* d_ws, size_t ws_size,
                              hipStream_t stream) {
    const float* z      = (const float*)d_in[0];
    const float* w_down = (const float*)d_in[1];
    const float* w_up   = (const float*)d_in[2];
    const float* emb    = (const float*)d_in[3];
    float* out = (float*)d_out;

    float* ws    = (float*)d_ws;
    float* Y     = ws + Y_OFF;
    float* Tab   = ws + Y_OFF;        // overlays Y after k_znorm (last Y reader)
    float* ET    = ws + ET_OFF;
    float* norms = ws + NORM_OFF;
    unsigned long long* best = (unsigned long long*)(ws + BEST_OFF);
    float* lossA = ws + LOSS_OFF;
    float* znorm = ws + ZN_OFF;

    hipMemsetAsync(best, 0xFF, (size_t)GG * NV * sizeof(unsigned long long), stream);
    hipMemsetAsync(lossA, 0, sizeof(float), stream);

    dim3 gdown(300, 6);
    k_gemm_down<<<gdown, 256, 0, stream>>>(z, w_down, Y);

    k_transpose<<<(GG * KK * DD + 255) / 256, 256, 0, stream>>>(emb, ET);
    k_norms<<<GG * KK, 64, 0, stream>>>(ET, norms);

    dim3 gdist(150, 8, GG);
    k_dist2<<<gdist, 256, 0, stream>>>(Y, ET, norms, best);

    k_znorm<<<14400, 256, 0, stream>>>(Y, znorm);
    k_sumloss<<<225, 256, 0, stream>>>(best, znorm, lossA);

    dim3 gtab(16, 12, 8);
    k_table<<<gtab, 256, 0, stream>>>(ET, w_up, Tab);

    dim3 gsc(24, 19, 32);
    k_scatter<<<gsc, 256, 0, stream>>>(Tab, best, out);

    k_finish<<<1, 64, 0, stream>>>(lossA, out);
}

// Round 8
// 2090.663 us; speedup vs baseline: 1.1225x; 1.1225x over previous
//
#include <hip/hip_runtime.h>

#define BB 32
#define CC 128
#define HH 12
#define WW 1200
#define DIN 1536
#define FIXD 768
#define OVL 4
#define GG 6
#define DD 512
#define KK 1024
#define TT 300
#define NV 9600        /* B*T vectors per group */
#define MROWS 38400    /* B*W */

// workspace layout (float offsets)
#define Y_OFF     0          /* 29,491,200 floats; Tab overlays this after k_dist2 */
#define ET_OFF    29491200
#define NORM_OFF  32636928
#define BEST_OFF  32643072   /* 57600 uint64 = 115200 floats */
#define LOSS_OFF  32758272
#define ZN_OFF    32758336   /* 57600 floats */

// LDS column swizzle for B-side tiles (placement-only)
#define BSWZ(c) ((c) + 4 * ((c) >> 5))

// ---------------- K1: proj_down fp32 GEMM, 128x128 tile, 8x8/thread ----------
// Y[n][f] = sum_k z[b*1843200 + k*1200 + w] * w_down[f*1536+k];  n = b*1200+w
// Accumulation is strictly k-sequential per output -> bit-identical Y to
// R3/R5/R6 (argmin-critical: do NOT change the fmaf chain order).
// Grid is (6 f-tiles, 300 n-tiles): x-fastest dispatch runs the 6 f-tiles of
// one z-panel consecutively -> z re-reads hit L3 (scheduling only).
__global__ __launch_bounds__(256) void k_gemm_down(const float* __restrict__ z,
                                                   const float* __restrict__ w_down,
                                                   float* __restrict__ Y) {
    __shared__ float As[16][132];
    __shared__ float Bs[16][140];
    const int n0 = blockIdx.y * 128, f0 = blockIdx.x * 128;
    const int tid = threadIdx.x;
    // A staging: row fixed per thread (128 rows), 8 k-slots (k = ak0 + 2*i)
    const int arow = tid & 127;
    const int ak0 = tid >> 7;           // 0..1
    const int nA = n0 + arow;
    const int bA = nA / WW, wA = nA - bA * WW;
    const size_t zbase = (size_t)bA * (CC * HH * WW) + wA;
    // B staging: col = tid>>1 (128 cols), two float4 (q = bq, bq+2)
    const int bcol = tid >> 1, bq = tid & 1;
    const int bsc = BSWZ(bcol);
    // compute thread grid 16x16
    const int trow = tid >> 4, tcol = tid & 15;
    const int bread = tcol * 8 + 4 * (tcol >> 2);
    float acc[8][8] = {};
    for (int kt = 0; kt < DIN; kt += 16) {
        #pragma unroll
        for (int i = 0; i < 8; i++) {
            const int kk = ak0 + i * 2;
            As[kk][arow] = z[zbase + (size_t)(kt + kk) * WW];
        }
        #pragma unroll
        for (int i = 0; i < 2; i++) {
            const int q = bq + i * 2;
            const float4 v = *(const float4*)&w_down[(size_t)(f0 + bcol) * DIN + kt + q * 4];
            Bs[q * 4 + 0][bsc] = v.x;
            Bs[q * 4 + 1][bsc] = v.y;
            Bs[q * 4 + 2][bsc] = v.z;
            Bs[q * 4 + 3][bsc] = v.w;
        }
        __syncthreads();
        #pragma unroll
        for (int k = 0; k < 16; k++) {
            float av[8], bv[8];
            *(float4*)&av[0] = *(const float4*)&As[k][trow * 8];
            *(float4*)&av[4] = *(const float4*)&As[k][trow * 8 + 4];
            *(float4*)&bv[0] = *(const float4*)&Bs[k][bread];
            *(float4*)&bv[4] = *(const float4*)&Bs[k][bread + 4];
            #pragma unroll
            for (int i = 0; i < 8; i++)
                #pragma unroll
                for (int j = 0; j < 8; j++)
                    acc[i][j] = fmaf(av[i], bv[j], acc[i][j]);
        }
        __syncthreads();
    }
    #pragma unroll
    for (int i = 0; i < 8; i++) {
        float4 o0, o1;
        o0.x = acc[i][0]; o0.y = acc[i][1]; o0.z = acc[i][2]; o0.w = acc[i][3];
        o1.x = acc[i][4]; o1.y = acc[i][5]; o1.z = acc[i][6]; o1.w = acc[i][7];
        float* yr = &Y[(size_t)(n0 + trow * 8 + i) * FIXD + f0 + tcol * 8];
        *(float4*)yr = o0;
        *(float4*)(yr + 4) = o1;
    }
}

// ---------------- K2: transpose codebook emb(g,d,k) -> ET(g,k,d) ----------------
__global__ __launch_bounds__(256) void k_transpose(const float* __restrict__ emb,
                                                   float* __restrict__ ET) {
    int i = blockIdx.x * 256 + threadIdx.x;
    if (i >= GG * KK * DD) return;
    int d = i & 511;
    int rem = i >> 9;
    int k = rem & 1023;
    int g = rem >> 10;
    ET[i] = emb[((g * DD + d) << 10) + k];
}

// ---------------- K2b: per-code squared norms (fp64 accumulate) ----------------
__global__ __launch_bounds__(64) void k_norms(const float* __restrict__ ET,
                                              float* __restrict__ norms) {
    const int code = blockIdx.x;
    const int lane = threadIdx.x;
    const float* row = ET + code * DD;
    double s = 0.0;
    #pragma unroll
    for (int r = 0; r < 8; r++) {
        float v = row[lane + r * 64];
        s += (double)v * (double)v;
    }
    #pragma unroll
    for (int off = 32; off; off >>= 1) s += __shfl_down(s, off);
    if (lane == 0) norms[code] = (float)s;
}

// ---------------- K3: distance GEMM + fused argmin + znorm fold --------------
// Scores are exact-fp32, d-sequential -> bit-identical to R5/R6 (argmin-critical).
// Grid (1200, 6): r = blockIdx.x decodes to a 48-block chunk {6 vt x 8 ct}
// so co-running blocks share Z/E panels (L2/L3 reuse; scheduling only).
// ct==0 blocks also accumulate znorm[v] = sum Y^2 during staging (loss path;
// loss tolerance is loose -- not argmin-relevant).
__global__ __launch_bounds__(256) void k_dist2(const float* __restrict__ Y,
                                               const float* __restrict__ ET,
                                               const float* __restrict__ norms,
                                               unsigned long long* __restrict__ best,
                                               float* __restrict__ znorm) {
    __shared__ float Zs[16][68];
    __shared__ float Es[16][140];
    __shared__ unsigned long long red[64][17];
    const int r = blockIdx.x;            // 0..1199
    const int g = blockIdx.y;            // 0..5
    const int chunk = r / 48;            // 25 chunks
    const int wi = r - chunk * 48;       // 0..47
    const int vt = chunk * 6 + (wi % 6); // 0..149
    const int ct = wi / 6;               // 0..7
    const int tid = threadIdx.x;
    const int rgrp = tid >> 4, cgrp = tid & 15;
    const int rbase = rgrp * 4;
    const int eread = cgrp * 8 + 4 * (cgrp >> 2);
    const int v0 = vt * 64, c0 = ct * 128;
    const float* ETg = ET + (size_t)g * KK * DD;

    const int zrow = tid >> 2, zq = tid & 3;
    const int vz = v0 + zrow;
    const int bz = vz / TT, tz = vz - bz * TT;

    float acc[4][8] = {};
    float zs = 0.0f;

    for (int kt = 0; kt < DD; kt += 16) {
        const int p0 = g * DD + kt;
        const int s = p0 / FIXD, f0 = p0 - s * FIXD;
        {
            const float4 v = *(const float4*)&Y[(bz * WW + tz * OVL + s) * FIXD + f0 + zq * 4];
            Zs[zq * 4 + 0][zrow] = v.x;
            Zs[zq * 4 + 1][zrow] = v.y;
            Zs[zq * 4 + 2][zrow] = v.z;
            Zs[zq * 4 + 3][zrow] = v.w;
            if (ct == 0) {
                zs = fmaf(v.x, v.x, zs);
                zs = fmaf(v.y, v.y, zs);
                zs = fmaf(v.z, v.z, zs);
                zs = fmaf(v.w, v.w, zs);
            }
        }
        #pragma unroll
        for (int i = 0; i < 2; i++) {
            int flat = tid + i * 256;
            int code = flat >> 2, q = flat & 3;
            const int sc = BSWZ(code);
            const float4 v = *(const float4*)&ETg[(size_t)(c0 + code) * DD + kt + q * 4];
            Es[q * 4 + 0][sc] = v.x;
            Es[q * 4 + 1][sc] = v.y;
            Es[q * 4 + 2][sc] = v.z;
            Es[q * 4 + 3][sc] = v.w;
        }
        __syncthreads();
        #pragma unroll
        for (int k = 0; k < 16; k++) {
            const float4 z4 = *(const float4*)&Zs[k][rbase];
            const float4 ea = *(const float4*)&Es[k][eread];
            const float4 eb = *(const float4*)&Es[k][eread + 4];
            const float zv[4] = {z4.x, z4.y, z4.z, z4.w};
            const float ev[8] = {ea.x, ea.y, ea.z, ea.w, eb.x, eb.y, eb.z, eb.w};
            #pragma unroll
            for (int i = 0; i < 4; i++)
                #pragma unroll
                for (int j = 0; j < 8; j++)
                    acc[i][j] = fmaf(zv[i], ev[j], acc[i][j]);
        }
        __syncthreads();
    }

    if (ct == 0) {
        float zsum = zs;
        zsum += __shfl_down(zsum, 2);
        zsum += __shfl_down(zsum, 1);
        if (zq == 0) znorm[g * NV + v0 + zrow] = zsum;
    }

    unsigned long long kbest[4];
    #pragma unroll
    for (int i = 0; i < 4; i++) kbest[i] = ~0ull;
    #pragma unroll
    for (int j = 0; j < 8; j++) {
        const int c = c0 + cgrp * 8 + j;
        const float nrm = norms[(g << 10) + c];
        #pragma unroll
        for (int i = 0; i < 4; i++) {
            float score = nrm - 2.0f * acc[i][j];
            unsigned u = __float_as_uint(score);
            u = (u & 0x80000000u) ? ~u : (u | 0x80000000u);
            unsigned long long key = ((unsigned long long)u << 32) | (unsigned)c;
            if (key < kbest[i]) kbest[i] = key;
        }
    }
    #pragma unroll
    for (int i = 0; i < 4; i++) red[rbase + i][cgrp] = kbest[i];
    __syncthreads();
    if (tid < 64) {
        unsigned long long b = red[tid][0];
        #pragma unroll
        for (int j = 1; j < 16; j++) {
            unsigned long long v = red[tid][j];
            if (v < b) b = v;
        }
        atomicMin(&best[g * NV + v0 + tid], b);
    }
}

// ---------------- K4: loss = sum_v (best_score_v + |z_v|^2) ------------------
// best key high word is a bijective monotone map of the fp32 score: decode it.
__global__ __launch_bounds__(256) void k_sumloss(const unsigned long long* __restrict__ best,
                                                 const float* __restrict__ znorm,
                                                 float* __restrict__ lossAcc) {
    const int v = blockIdx.x * 256 + threadIdx.x;        // 225 blocks * 256 = 57600
    const unsigned long long key = best[v];
    const unsigned u = (unsigned)(key >> 32);
    const unsigned x = (u & 0x80000000u) ? (u & 0x7fffffffu) : ~u;
    float s = __uint_as_float(x) + znorm[v];
    __shared__ float red[256];
    red[threadIdx.x] = s;
    __syncthreads();
    for (int off = 128; off; off >>= 1) {
        if (threadIdx.x < off) red[threadIdx.x] += red[threadIdx.x + off];
        __syncthreads();
    }
    if (threadIdx.x == 0) atomicAdd(lossAcc, red[0]);
}

// ---------------- K5a: per-(segment,code) up-projection table ----------------
__constant__ int SEG_G[8]  = {0, 1, 1, 2, 3, 4, 4, 5};
__constant__ int SEG_D0[8] = {0, 0, 256, 0, 0, 0, 256, 0};
__constant__ int SEG_L[8]  = {512, 256, 256, 512, 512, 256, 256, 512};
__constant__ int SEG_F0[8] = {0, 512, 0, 256, 0, 512, 0, 256};

__global__ __launch_bounds__(256) void k_table(const float* __restrict__ ET,
                                               const float* __restrict__ w_up,
                                               float* __restrict__ Tab) {
    __shared__ float As[16][68];
    __shared__ float Bs[16][140];
    const int bm = blockIdx.x;
    const int bn = blockIdx.y;
    const int seg = blockIdx.z;
    const int g = SEG_G[seg], d0 = SEG_D0[seg], len = SEG_L[seg], fb = SEG_F0[seg];
    const int tid = threadIdx.x;
    const int k0 = bm * 64, dout0 = bn * 128;
    const int arow = tid >> 2, aq = tid & 3;
    const int rbase = (tid >> 4) << 2;
    const int cgrp = tid & 15;
    const int bread = cgrp * 8 + 4 * (cgrp >> 2);
    const float* ETg = ET + (size_t)(g << 10) * DD;
    float acc[4][8] = {};
    for (int kt = 0; kt < len; kt += 16) {
        {
            const float4 v = *(const float4*)&ETg[(size_t)(k0 + arow) * DD + d0 + kt + aq * 4];
            As[aq * 4 + 0][arow] = v.x;
            As[aq * 4 + 1][arow] = v.y;
            As[aq * 4 + 2][arow] = v.z;
            As[aq * 4 + 3][arow] = v.w;
        }
        #pragma unroll
        for (int i = 0; i < 2; i++) {
            int fl = tid + i * 256;
            int col = fl >> 2, q = fl & 3;
            const int sc = BSWZ(col);
            const float4 v = *(const float4*)&w_up[(size_t)(dout0 + col) * FIXD + fb + kt + q * 4];
            Bs[q * 4 + 0][sc] = v.x;
            Bs[q * 4 + 1][sc] = v.y;
            Bs[q * 4 + 2][sc] = v.z;
            Bs[q * 4 + 3][sc] = v.w;
        }
        __syncthreads();
        #pragma unroll
        for (int k = 0; k < 16; k++) {
            const float4 a  = *(const float4*)&As[k][rbase];
            const float4 ba = *(const float4*)&Bs[k][bread];
            const float4 bb = *(const float4*)&Bs[k][bread + 4];
            const float av[4] = {a.x, a.y, a.z, a.w};
            const float bv[8] = {ba.x, ba.y, ba.z, ba.w, bb.x, bb.y, bb.z, bb.w};
            #pragma unroll
            for (int i = 0; i < 4; i++)
                #pragma unroll
                for (int j = 0; j < 8; j++)
                    acc[i][j] = fmaf(av[i], bv[j], acc[i][j]);
        }
        __syncthreads();
    }
    #pragma unroll
    for (int i = 0; i < 4; i++) {
        float4 o0, o1;
        o0.x = acc[i][0]; o0.y = acc[i][1]; o0.z = acc[i][2]; o0.w = acc[i][3];
        o1.x = acc[i][4]; o1.y = acc[i][5]; o1.z = acc[i][6]; o1.w = acc[i][7];
        float* tr = &Tab[(size_t)((seg << 10) + k0 + rbase + i) * DIN + dout0 + cgrp * 8];
        *(float4*)tr = o0;
        *(float4*)(tr + 4) = o1;
    }
}

// ---------------- K5b: gather-add scatter to output ----------------
__global__ __launch_bounds__(256) void k_scatter(const float* __restrict__ Tab,
                                                 const unsigned long long* __restrict__ best,
                                                 float* __restrict__ out) {
    __shared__ float Ls[64][65];
    const int dt = blockIdx.x;
    const int wt = blockIdx.y;
    const int b  = blockIdx.z;
    const int dout0 = dt * 64, w0 = wt * 64;
    const int wlim = (WW - w0 < 64) ? (WW - w0) : 64;
    const int tid = threadIdx.x;
    const int wi = tid >> 2, q = tid & 3;

    if (wi < wlim) {
        const int w = w0 + wi;
        const int s = w & 3;
        const int t = w >> 2;
        const int gEt[4] = {0, 1, 3, 4};
        const int gOt[4] = {1, 2, 4, 5};
        int ce = (int)(unsigned)best[gEt[s] * NV + b * TT + t];
        int co = (int)(unsigned)best[gOt[s] * NV + b * TT + t];
        size_t rowE = (size_t)(((2 * s) << 10) + ce) * DIN;
        size_t rowO = (size_t)(((2 * s + 1) << 10) + co) * DIN;
        #pragma unroll
        for (int rep = 0; rep < 4; rep++) {
            const int doff = rep * 16 + q * 4;
            const float4 a = *(const float4*)&Tab[rowE + dout0 + doff];
            const float4 c = *(const float4*)&Tab[rowO + dout0 + doff];
            Ls[wi][doff + 0] = a.x + c.x;
            Ls[wi][doff + 1] = a.y + c.y;
            Ls[wi][doff + 2] = a.z + c.z;
            Ls[wi][doff + 3] = a.w + c.w;
        }
    }
    __syncthreads();
    const size_t obase = (size_t)b * (CC * HH * WW) + (size_t)dout0 * WW + w0;
    #pragma unroll
    for (int i = 0; i < 16; i++) {
        int flat = tid + i * 256;
        int dr = flat >> 6, wj = flat & 63;
        if (wj < wlim) out[obase + (size_t)dr * WW + wj] = Ls[wj][dr];
    }
}

// ---------------- K6: finalize loss scalar ----------------
__global__ void k_finish(const float* __restrict__ lossAcc, float* __restrict__ out) {
    if (threadIdx.x == 0)
        out[58982400] = lossAcc[0] * (0.25f / 29491200.0f);
}

extern "C" void kernel_launch(void* const* d_in, const int* in_sizes, int n_in,
                              void* d_out, int out_size, void* d_ws, size_t ws_size,
                              hipStream_t stream) {
    const float* z      = (const float*)d_in[0];
    const float* w_down = (const float*)d_in[1];
    const float* w_up   = (const float*)d_in[2];
    const float* emb    = (const float*)d_in[3];
    float* out = (float*)d_out;

    float* ws    = (float*)d_ws;
    float* Y     = ws + Y_OFF;
    float* Tab   = ws + Y_OFF;        // overlays Y after k_dist2 (last Y reader)
    float* ET    = ws + ET_OFF;
    float* norms = ws + NORM_OFF;
    unsigned long long* best = (unsigned long long*)(ws + BEST_OFF);
    float* lossA = ws + LOSS_OFF;
    float* znorm = ws + ZN_OFF;

    hipMemsetAsync(best, 0xFF, (size_t)GG * NV * sizeof(unsigned long long), stream);
    hipMemsetAsync(lossA, 0, sizeof(float), stream);

    dim3 gdown(6, 300);
    k_gemm_down<<<gdown, 256, 0, stream>>>(z, w_down, Y);

    k_transpose<<<(GG * KK * DD + 255) / 256, 256, 0, stream>>>(emb, ET);
    k_norms<<<GG * KK, 64, 0, stream>>>(ET, norms);

    dim3 gdist(1200, GG);
    k_dist2<<<gdist, 256, 0, stream>>>(Y, ET, norms, best, znorm);

    k_sumloss<<<225, 256, 0, stream>>>(best, znorm, lossA);

    dim3 gtab(16, 12, 8);
    k_table<<<gtab, 256, 0, stream>>>(ET, w_up, Tab);

    dim3 gsc(24, 19, 32);
    k_scatter<<<gsc, 256, 0, stream>>>(Tab, best, out);

    k_finish<<<1, 64, 0, stream>>>(lossA, out);
}